// Round 4
// baseline (548.309 us; speedup 1.0000x reference)
//
#include <hip/hip_runtime.h>

typedef __bf16 bf16;
typedef bf16 bf16x8 __attribute__((ext_vector_type(8)));
typedef bf16 bf16x4 __attribute__((ext_vector_type(4)));
typedef float f32x4 __attribute__((ext_vector_type(4)));
typedef short s16x4 __attribute__((ext_vector_type(4)));

#define AS1 __attribute__((address_space(1)))
#define AS3 __attribute__((address_space(3)))

__device__ __forceinline__ void load_lds16(const void* g, void* l) {
    __builtin_amdgcn_global_load_lds((const AS1 unsigned int*)g,
                                     (AS3 unsigned int*)l, 16, 0, 0);
}

// ---------------------------------------------------------------------------
// cast fp32 -> bf16 (vectorized)
// ---------------------------------------------------------------------------
__global__ __launch_bounds__(256) void cast_f32_bf16(
        const float* __restrict__ in, bf16* __restrict__ out, int n) {
    int i = (blockIdx.x * 256 + threadIdx.x) * 4;
    if (i < n) {
        float4 v = *(const float4*)(in + i);
        bf16x4 o = { (bf16)v.x, (bf16)v.y, (bf16)v.z, (bf16)v.w };
        *(bf16x4*)(out + i) = o;
    }
}

// ---------------------------------------------------------------------------
// transpose + cast: in fp32 [K][N] -> out bf16 [Np][K]; rows n in [N,Np) = 0
// ---------------------------------------------------------------------------
__global__ __launch_bounds__(256) void transpose_cast(
        const float* __restrict__ in, bf16* __restrict__ out,
        int K, int N, int Np) {
    __shared__ float tile[32][33];
    int bx = blockIdx.x * 32;  // n (output row)
    int by = blockIdx.y * 32;  // k
    int tx = threadIdx.x, ty = threadIdx.y;  // 32 x 8
#pragma unroll
    for (int i = 0; i < 4; ++i) {
        int k = by + ty + i * 8, n = bx + tx;
        float v = (k < K && n < N) ? in[(size_t)k * N + n] : 0.f;
        tile[ty + i * 8][tx] = v;
    }
    __syncthreads();
#pragma unroll
    for (int i = 0; i < 4; ++i) {
        int n = bx + ty + i * 8, k = by + tx;
        if (n < Np && k < K) out[(size_t)n * K + k] = (bf16)tile[tx][ty + i * 8];
    }
}

// ---------------------------------------------------------------------------
// transpose V slice of kvb -> vtb[(b*16+h)*128 + vd][kv]  (bf16 -> bf16)
// ---------------------------------------------------------------------------
__global__ __launch_bounds__(256) void transpose_v(
        const bf16* __restrict__ kvb, bf16* __restrict__ vtb) {
    __shared__ bf16 t[32][34];
    const int kv0 = blockIdx.x * 32;
    const int vd0 = blockIdx.y * 32;
    const int bh = blockIdx.z;                 // b*16 + h
    const int b = bh >> 4, h = bh & 15;
    const int tx = threadIdx.x, ty = threadIdx.y;  // 32 x 8
#pragma unroll
    for (int i = 0; i < 4; ++i)
        t[ty + i * 8][tx] = kvb[(size_t)(b * 2048 + kv0 + ty + i * 8) * 4096
                                + h * 256 + 128 + vd0 + tx];
    __syncthreads();
#pragma unroll
    for (int i = 0; i < 4; ++i)
        vtb[(size_t)(bh * 128 + vd0 + ty + i * 8) * 2048 + kv0 + tx] =
            t[tx][ty + i * 8];
}

// ---------------------------------------------------------------------------
// GEMM: C[M][N] = A[M][K] * Bt[N][K]^T . 128x128 tile, BK=64, 4 waves.
// ---------------------------------------------------------------------------
template <typename OutT>
__global__ __launch_bounds__(256) void gemm_bt(
        const bf16* __restrict__ A, const bf16* __restrict__ Bt,
        OutT* __restrict__ C, int K, int lda, int ldb, int ldc) {
    __shared__ __align__(16) bf16 As[128 * 64];
    __shared__ __align__(16) bf16 Bs[128 * 64];
    const int tid = threadIdx.x;
    const int wave = tid >> 6, lane = tid & 63;
    const int l15 = lane & 15, quad = lane >> 4;
    const int m0 = blockIdx.y * 128, n0 = blockIdx.x * 128;
    const int wm = (wave >> 1) * 64, wn = (wave & 1) * 64;

    f32x4 acc[4][4] = {};

    for (int k0 = 0; k0 < K; k0 += 64) {
#pragma unroll
        for (int c = 0; c < 4; ++c) {
            int e = wave * 2048 + c * 512 + lane * 8;
            int r = e >> 6, col = e & 63;
            load_lds16(A + (size_t)(m0 + r) * lda + k0 + col,
                       &As[wave * 2048 + c * 512]);
            load_lds16(Bt + (size_t)(n0 + r) * ldb + k0 + col,
                       &Bs[wave * 2048 + c * 512]);
        }
        __syncthreads();
#pragma unroll
        for (int kk = 0; kk < 64; kk += 32) {
            bf16x8 af[4], bf[4];
#pragma unroll
            for (int i = 0; i < 4; ++i)
                af[i] = *(const bf16x8*)&As[(wm + i * 16 + l15) * 64 + kk + quad * 8];
#pragma unroll
            for (int j = 0; j < 4; ++j)
                bf[j] = *(const bf16x8*)&Bs[(wn + j * 16 + l15) * 64 + kk + quad * 8];
#pragma unroll
            for (int i = 0; i < 4; ++i)
#pragma unroll
                for (int j = 0; j < 4; ++j)
                    acc[i][j] = __builtin_amdgcn_mfma_f32_16x16x32_bf16(
                        af[i], bf[j], acc[i][j], 0, 0, 0);
        }
        __syncthreads();
    }
#pragma unroll
    for (int i = 0; i < 4; ++i)
#pragma unroll
        for (int j = 0; j < 4; ++j) {
            int row = m0 + wm + i * 16 + quad * 4;
            int col = n0 + wn + j * 16 + l15;
#pragma unroll
            for (int r = 0; r < 4; ++r)
                C[(size_t)(row + r) * ldc + col] = (OutT)acc[i][j][r];
        }
}

// ---------------------------------------------------------------------------
// Fused down-proj GEMM: Bt rows [0,768)=w_q_down^T -> C1, [768,1408)=w_kv_down^T -> C2
// ---------------------------------------------------------------------------
__global__ __launch_bounds__(256) void gemm_down(
        const bf16* __restrict__ A, const bf16* __restrict__ Bt,
        bf16* __restrict__ C1, bf16* __restrict__ C2) {
    const int K = 2048, lda = 2048, ldb = 2048;
    __shared__ __align__(16) bf16 As[128 * 64];
    __shared__ __align__(16) bf16 Bs[128 * 64];
    const int tid = threadIdx.x;
    const int wave = tid >> 6, lane = tid & 63;
    const int l15 = lane & 15, quad = lane >> 4;
    const int m0 = blockIdx.y * 128, n0 = blockIdx.x * 128;
    const int wm = (wave >> 1) * 64, wn = (wave & 1) * 64;

    f32x4 acc[4][4] = {};

    for (int k0 = 0; k0 < K; k0 += 64) {
#pragma unroll
        for (int c = 0; c < 4; ++c) {
            int e = wave * 2048 + c * 512 + lane * 8;
            int r = e >> 6, col = e & 63;
            load_lds16(A + (size_t)(m0 + r) * lda + k0 + col,
                       &As[wave * 2048 + c * 512]);
            load_lds16(Bt + (size_t)(n0 + r) * ldb + k0 + col,
                       &Bs[wave * 2048 + c * 512]);
        }
        __syncthreads();
#pragma unroll
        for (int kk = 0; kk < 64; kk += 32) {
            bf16x8 af[4], bf[4];
#pragma unroll
            for (int i = 0; i < 4; ++i)
                af[i] = *(const bf16x8*)&As[(wm + i * 16 + l15) * 64 + kk + quad * 8];
#pragma unroll
            for (int j = 0; j < 4; ++j)
                bf[j] = *(const bf16x8*)&Bs[(wn + j * 16 + l15) * 64 + kk + quad * 8];
#pragma unroll
            for (int i = 0; i < 4; ++i)
#pragma unroll
                for (int j = 0; j < 4; ++j)
                    acc[i][j] = __builtin_amdgcn_mfma_f32_16x16x32_bf16(
                        af[i], bf[j], acc[i][j], 0, 0, 0);
        }
        __syncthreads();
    }
    bf16* Cp; int ldc, coff;
    if (n0 < 768) { Cp = C1; ldc = 768; coff = 0; }
    else          { Cp = C2; ldc = 640; coff = 768; }
#pragma unroll
    for (int i = 0; i < 4; ++i)
#pragma unroll
        for (int j = 0; j < 4; ++j) {
            int row = m0 + wm + i * 16 + quad * 4;
            int col = n0 + wn + j * 16 + l15 - coff;
#pragma unroll
            for (int r = 0; r < 4; ++r)
                Cp[(size_t)(row + r) * ldc + col] = (bf16)acc[i][j][r];
        }
}

// ---------------------------------------------------------------------------
// Flash attention (causal), S^T formulation, 4 waves / 64 q-rows per block.
// Grid: (32, H, B) reversed-x (heavy first); 1024 blocks, 40 KB LDS
// -> 4 blocks/CU = 16 waves/CU.
// Per 64-kv tile, fully latency-hidden staging:
//   regs(kt) -> LDS (b128/b64, frag-major, conflict-free); barrier;
//   issue plain global loads for kt+1 into regs; compute kt.
// The loads for kt+1 drain at the *next* tile's barrier, a full compute
// phase later -> no exposed global latency (fixes R3's DMA-drain stall).
// V is pre-transposed globally (transpose_v) -> no per-tile scalar LDS.
// Mask applied only on the diagonal tile (wave-uniform).
// ---------------------------------------------------------------------------
__global__ __launch_bounds__(256) void mla_attention(
        const bf16* __restrict__ qb, const bf16* __restrict__ kvb,
        const bf16* __restrict__ cb, const bf16* __restrict__ vtb,
        bf16* __restrict__ ob) {
    constexpr int S = 2048;
    const int qt = gridDim.x - 1 - blockIdx.x;   // heavy blocks first
    const int h = blockIdx.y, b = blockIdx.z;
    const int q0 = qt * 64;
    const int tid = threadIdx.x, wave = tid >> 6, lane = tid & 63;
    const int l15 = lane & 15, quad = lane >> 4;

    // fragment-major tiles: K block (mt,ks)=16kv x 32feat (1 KB);
    // V block (nt,ktk)=16vd x 16kv (512 B)
    __shared__ __align__(16) bf16 Ks[24 * 512];  // 24 KB
    __shared__ __align__(16) bf16 Vs[32 * 256];  // 16 KB

    const int qrow = q0 + wave * 16 + l15;
    bf16x8 qf[6];
    {
        const bf16* qr = qb + (size_t)(b * S + qrow) * 3072 + h * 192;
#pragma unroll
        for (int ks = 0; ks < 6; ++ks)
            qf[ks] = *(const bf16x8*)(qr + ks * 32 + quad * 8);
    }

    f32x4 o[8] = {};
    float m_i = -1e30f, l_i = 0.f;
    const float sm_scale = 0.08838834764831845f * 1.4426950408889634f;
    const int ntiles = qt + 1;

    const bf16* vt_base = vtb + (size_t)((b * 16 + h) * 128) * 2048;

    // prefetch registers: wave w stages K rows mt=w (6 col-chunks) and
    // V blocks nt={2w,2w+1} x ktk 0..3
    bf16x8 kreg[6];
    bf16x4 vreg[8];
    {
        const size_t krow = (size_t)(b * S + 0 + wave * 16 + l15);
        const bf16* kn = kvb + krow * 4096 + h * 256 + quad * 8;
        const bf16* kr = cb + krow * 640 + 512 + quad * 8;
#pragma unroll
        for (int i = 0; i < 6; ++i)
            kreg[i] = (i < 4) ? *(const bf16x8*)(kn + i * 32)
                              : *(const bf16x8*)(kr + (i - 4) * 32);
#pragma unroll
        for (int i = 0; i < 8; ++i) {
            int nt = wave * 2 + (i >> 2), ktk = i & 3;
            vreg[i] = *(const bf16x4*)(vt_base + (size_t)(nt * 16 + l15) * 2048
                                       + ktk * 16 + quad * 4);
        }
    }

    for (int kt = 0; kt < ntiles; ++kt) {
        const int kv0 = kt * 64;
        __syncthreads();   // all waves done reading LDS of prev tile
#pragma unroll
        for (int i = 0; i < 6; ++i)
            *(bf16x8*)&Ks[(wave * 6 + i) * 512 + lane * 8] = kreg[i];
#pragma unroll
        for (int i = 0; i < 8; ++i)
            *(bf16x4*)&Vs[(wave * 8 + i) * 256 + lane * 4] = vreg[i];
        __syncthreads();   // LDS visible; no outstanding loads here

        if (kt + 1 < ntiles) {   // issue next tile's loads (drain next barrier)
            const size_t krow = (size_t)(b * S + kv0 + 64 + wave * 16 + l15);
            const bf16* kn = kvb + krow * 4096 + h * 256 + quad * 8;
            const bf16* kr = cb + krow * 640 + 512 + quad * 8;
#pragma unroll
            for (int i = 0; i < 6; ++i)
                kreg[i] = (i < 4) ? *(const bf16x8*)(kn + i * 32)
                                  : *(const bf16x8*)(kr + (i - 4) * 32);
#pragma unroll
            for (int i = 0; i < 8; ++i) {
                int nt = wave * 2 + (i >> 2), ktk = i & 3;
                vreg[i] = *(const bf16x4*)(vt_base + (size_t)(nt * 16 + l15) * 2048
                                           + kv0 + 64 + ktk * 16 + quad * 4);
            }
        }

        // S^T = K * Q^T ; C-layout: row(quad*4+r)=kv, col(l15)=qrow
        f32x4 s[4];
#pragma unroll
        for (int mt = 0; mt < 4; ++mt) {
            f32x4 a = {};
#pragma unroll
            for (int ks = 0; ks < 6; ++ks) {
                bf16x8 kf = *(const bf16x8*)&Ks[(mt * 6 + ks) * 512 + lane * 8];
                a = __builtin_amdgcn_mfma_f32_16x16x32_bf16(kf, qf[ks], a, 0, 0, 0);
            }
            s[mt] = a;
        }

        // online softmax: lane owns qrow=l15's 16 kv values
        float mx = -1e30f;
        if (kt == ntiles - 1) {   // diagonal tile: apply causal mask
#pragma unroll
            for (int mt = 0; mt < 4; ++mt)
#pragma unroll
                for (int r = 0; r < 4; ++r) {
                    int kvi = kv0 + mt * 16 + quad * 4 + r;
                    float v = (kvi <= qrow) ? s[mt][r] * sm_scale : -1e30f;
                    s[mt][r] = v;
                    mx = fmaxf(mx, v);
                }
        } else {
#pragma unroll
            for (int mt = 0; mt < 4; ++mt)
#pragma unroll
                for (int r = 0; r < 4; ++r) {
                    float v = s[mt][r] * sm_scale;
                    s[mt][r] = v;
                    mx = fmaxf(mx, v);
                }
        }
        mx = fmaxf(mx, __shfl_xor(mx, 16, 64));
        mx = fmaxf(mx, __shfl_xor(mx, 32, 64));
        float m_new = fmaxf(m_i, mx);
        float su = 0.f;
        bf16x4 pf[4];
#pragma unroll
        for (int mt = 0; mt < 4; ++mt)
#pragma unroll
            for (int r = 0; r < 4; ++r) {
                float p = exp2f(s[mt][r] - m_new);
                su += p;
                pf[mt][r] = (bf16)p;
            }
        su += __shfl_xor(su, 16, 64);
        su += __shfl_xor(su, 32, 64);
        float alpha = exp2f(m_i - m_new);
        l_i = l_i * alpha + su;
        m_i = m_new;
        float alpha_r[4];
#pragma unroll
        for (int r = 0; r < 4; ++r) alpha_r[r] = __shfl(alpha, quad * 4 + r, 64);
#pragma unroll
        for (int nt = 0; nt < 8; ++nt)
#pragma unroll
            for (int r = 0; r < 4; ++r) o[nt][r] *= alpha_r[r];

        // O += P * V  (P already in A-layout regs; V b64 frag reads)
#pragma unroll
        for (int ktk = 0; ktk < 4; ++ktk) {
            s16x4 a = __builtin_bit_cast(s16x4, pf[ktk]);
#pragma unroll
            for (int nt = 0; nt < 8; ++nt) {
                s16x4 bfv = __builtin_bit_cast(s16x4,
                    *(const bf16x4*)&Vs[(nt * 4 + ktk) * 256 + lane * 4]);
                o[nt] = __builtin_amdgcn_mfma_f32_16x16x16bf16_1k(a, bfv, o[nt], 0, 0, 0);
            }
        }
    }

    // epilogue
    float l_r[4];
#pragma unroll
    for (int r = 0; r < 4; ++r) l_r[r] = __shfl(l_i, quad * 4 + r, 64);
    bf16* obase = ob + (size_t)(b * S + q0 + wave * 16) * 2048 + h * 128;
#pragma unroll
    for (int nt = 0; nt < 8; ++nt)
#pragma unroll
        for (int r = 0; r < 4; ++r)
            obase[(size_t)(quad * 4 + r) * 2048 + nt * 16 + l15] =
                (bf16)(o[nt][r] / l_r[r]);
}

// ---------------------------------------------------------------------------
// launch
// ---------------------------------------------------------------------------
extern "C" void kernel_launch(void* const* d_in, const int* in_sizes, int n_in,
                              void* d_out, int out_size, void* d_ws, size_t ws_size,
                              hipStream_t stream) {
    const float* x    = (const float*)d_in[0];
    const float* wqd  = (const float*)d_in[3];
    const float* wqu  = (const float*)d_in[4];
    const float* wkvd = (const float*)d_in[5];
    const float* wkvu = (const float*)d_in[6];
    const float* wout = (const float*)d_in[7];
    float* out = (float*)d_out;
    char* ws = (char*)d_ws;

    bf16* xb    = (bf16*)(ws + 0);          // 4096x2048 ; reused as vtb after gemm_down
    bf16* vtb   = (bf16*)(ws + 0);          // [b][h][128][2048] (aliases xb)
    bf16* wqdT  = (bf16*)(ws + 16777216);   // 768x2048   (adjacent to wkvdT!)
    bf16* wkvdT = (bf16*)(ws + 19922944);   // 640x2048
    bf16* wquT  = (bf16*)(ws + 22544384);   // 3072x768
    bf16* wkvuT = (bf16*)(ws + 27262976);   // 4096x512
    bf16* woutT = (bf16*)(ws + 31457280);   // 2048x2048
    bf16* qd    = (bf16*)(ws + 39845888);   // 4096x768
    bf16* qb    = (bf16*)(ws + 46137344);   // 4096x3072
    bf16* cb    = (bf16*)(ws + 71303168);   // 4096x640
    bf16* kvb   = (bf16*)(ws + 76546048);   // 4096x4096
    bf16* attnb = (bf16*)(ws + 110100480);  // 4096x2048

    dim3 tb(32, 8);
    cast_f32_bf16<<<8192, 256, 0, stream>>>(x, xb, 8388608);
    transpose_cast<<<dim3(24, 64),  tb, 0, stream>>>(wqd,  wqdT,  2048, 768,  768);
    transpose_cast<<<dim3(20, 64),  tb, 0, stream>>>(wkvd, wkvdT, 2048, 576,  640);
    transpose_cast<<<dim3(96, 24),  tb, 0, stream>>>(wqu,  wquT,  768,  3072, 3072);
    transpose_cast<<<dim3(128, 16), tb, 0, stream>>>(wkvu, wkvuT, 512,  4096, 4096);
    transpose_cast<<<dim3(64, 64),  tb, 0, stream>>>(wout, woutT, 2048, 2048, 2048);

    gemm_down<<<dim3(11, 32), 256, 0, stream>>>(xb, wqdT, qd, cb);   // last reader of xb
    gemm_bt<bf16><<<dim3(24, 32), 256, 0, stream>>>(qd, wquT,  qb,  768, 768, 768, 3072);
    gemm_bt<bf16><<<dim3(32, 32), 256, 0, stream>>>(cb, wkvuT, kvb, 512, 640, 512, 4096);

    transpose_v<<<dim3(64, 4, 32), tb, 0, stream>>>(kvb, vtb);

    mla_attention<<<dim3(32, 16, 2), 256, 0, stream>>>(qb, kvb, cb, vtb, attnb);

    gemm_bt<float><<<dim3(16, 32), 256, 0, stream>>>(attnb, woutT, out, 2048, 2048, 2048, 2048);
}